// Round 9
// baseline (312.000 us; speedup 1.0000x reference)
//
#include <hip/hip_runtime.h>
#include <hip/hip_bf16.h>
#include <math.h>

// Problem constants
#define Bn 2
#define Tn 2048
#define Cn 768
#define Hn 12
#define HDn 64
#define D2n 32
#define FFn 3072
#define EPSn 1e-5f
#define QKVS (3 * Cn)  // 2304
#define LOG2E 1.4426950408889634f

typedef short s16x8 __attribute__((ext_vector_type(8)));
typedef float f32x4 __attribute__((ext_vector_type(4)));
typedef unsigned short u16;

__device__ __forceinline__ u16 f2bf(float f) {
    union { float f; unsigned u; } v;
    v.f = f;
    unsigned r = (v.u + 0x7fffu + ((v.u >> 16) & 1u)) >> 16;
    return (u16)r;
}
__device__ __forceinline__ float bf2f(u16 u) {
    union { unsigned u; float f; } v;
    v.u = ((unsigned)u) << 16;
    return v.f;
}
__device__ __forceinline__ unsigned pack2(float a, float b) {
    union { float f; unsigned u; } va, vb;
    va.f = a; vb.f = b;
    return (va.u >> 16) | (vb.u & 0xffff0000u);  // trunc-to-bf16 pair
}

__device__ __forceinline__ void gl2lds16(const void* g, void* l) {
    __builtin_amdgcn_global_load_lds((const __attribute__((address_space(1))) void*)g,
                                     (__attribute__((address_space(3))) void*)l,
                                     16, 0, 0);
}

// ---------------- RMSNorm -> bf16 out: one block per row ------------------------
__global__ __launch_bounds__(256) void rmsnorm_bf16_kernel(const float* __restrict__ x,
                                                           const float* __restrict__ g,
                                                           u16* __restrict__ out) {
    int row = blockIdx.x;
    const float* xr = x + (size_t)row * Cn;
    u16* orow = out + (size_t)row * Cn;
    int tid = threadIdx.x;
    float v[3];
    float ss = 0.f;
#pragma unroll
    for (int i = 0; i < 3; ++i) {
        v[i] = xr[tid + 256 * i];
        ss += v[i] * v[i];
    }
#pragma unroll
    for (int o = 32; o; o >>= 1) ss += __shfl_xor(ss, o);
    __shared__ float red[4];
    int w = tid >> 6;
    if ((tid & 63) == 0) red[w] = ss;
    __syncthreads();
    float tot = red[0] + red[1] + red[2] + red[3];
    float s = rsqrtf(tot / (float)Cn + EPSn);
#pragma unroll
    for (int i = 0; i < 3; ++i) {
        int c = tid + 256 * i;
        orow[c] = f2bf(g[c] * v[i] * s);
    }
}

// ---------------- Fused: x1 = x + p0 + p1 ; h2 = rmsnorm(x1, g) -----------------
__global__ __launch_bounds__(256) void reduce2_rmsnorm_kernel(const float* __restrict__ p0,
                                                              const float* __restrict__ p1,
                                                              const float* __restrict__ x,
                                                              const float* __restrict__ g,
                                                              float* __restrict__ x1,
                                                              u16* __restrict__ h2) {
    int row = blockIdx.x;
    size_t base = (size_t)row * Cn;
    int tid = threadIdx.x;
    float v[3];
    float ss = 0.f;
#pragma unroll
    for (int i = 0; i < 3; ++i) {
        size_t c = base + tid + 256 * i;
        float t = x[c] + p0[c] + p1[c];
        v[i] = t;
        ss += t * t;
    }
#pragma unroll
    for (int o = 32; o; o >>= 1) ss += __shfl_xor(ss, o);
    __shared__ float red[4];
    int w = tid >> 6;
    if ((tid & 63) == 0) red[w] = ss;
    __syncthreads();
    float tot = red[0] + red[1] + red[2] + red[3];
    float s = rsqrtf(tot / (float)Cn + EPSn);
#pragma unroll
    for (int i = 0; i < 3; ++i) {
        int c = tid + 256 * i;
        x1[base + c] = v[i];
        h2[base + c] = f2bf(g[c] * v[i] * s);
    }
}

// ---------------- Final reduce: out = x1 + q0 + qrest[0] + qrest[1] -------------
__global__ __launch_bounds__(256) void reduce_final_kernel(const float* __restrict__ q0,
                                                           const float* __restrict__ qrest,
                                                           const float* __restrict__ x1,
                                                           float* __restrict__ out) {
    const size_t MN = (size_t)Bn * Tn * Cn;
    size_t i = ((size_t)blockIdx.x * 256 + threadIdx.x) * 4;
    float4 a = *(const float4*)&x1[i];
    float4 b = *(const float4*)&q0[i];
    float4 c = *(const float4*)&qrest[i];
    float4 d = *(const float4*)&qrest[MN + i];
    float4 r;
    r.x = a.x + b.x + c.x + d.x;
    r.y = a.y + b.y + c.y + d.y;
    r.z = a.z + b.z + c.z + d.z;
    r.w = a.w + b.w + c.w + d.w;
    *(float4*)&out[i] = r;
}

// ---------------- All weight transposes in ONE launch ---------------------------
__global__ __launch_bounds__(256) void transpose_all_kernel(const float* __restrict__ wq,
                                                            const float* __restrict__ wk,
                                                            const float* __restrict__ wv,
                                                            const float* __restrict__ wo,
                                                            const float* __restrict__ wfc,
                                                            const float* __restrict__ wpr,
                                                            u16* __restrict__ wt_qkv,
                                                            u16* __restrict__ wt_o,
                                                            u16* __restrict__ wt_fc,
                                                            u16* __restrict__ wt_pr) {
    int id = blockIdx.x;
    const float* W;
    u16* Wt;
    int K, N, lid;
    if (id < 576)       { W = wq;  Wt = wt_qkv;                      K = Cn;  N = Cn;  lid = id; }
    else if (id < 1152) { W = wk;  Wt = wt_qkv + (size_t)Cn * Cn;    K = Cn;  N = Cn;  lid = id - 576; }
    else if (id < 1728) { W = wv;  Wt = wt_qkv + (size_t)2 * Cn * Cn;K = Cn;  N = Cn;  lid = id - 1152; }
    else if (id < 2304) { W = wo;  Wt = wt_o;                        K = Cn;  N = Cn;  lid = id - 1728; }
    else if (id < 4608) { W = wfc; Wt = wt_fc;                       K = Cn;  N = FFn; lid = id - 2304; }
    else                { W = wpr; Wt = wt_pr;                       K = FFn; N = Cn;  lid = id - 4608; }
    int ntx = N / 32;
    int bx = (lid % ntx) * 32;
    int by = (lid / ntx) * 32;

    __shared__ u16 t[32][33];
    int tx = threadIdx.x & 31, ty = threadIdx.x >> 5;
#pragma unroll
    for (int i = 0; i < 4; ++i) {
        int kk = by + ty + i * 8;
        t[ty + i * 8][tx] = f2bf(W[(size_t)kk * N + bx + tx]);
    }
    __syncthreads();
#pragma unroll
    for (int i = 0; i < 4; ++i) {
        int n = bx + ty + i * 8;
        Wt[(size_t)n * K + by + tx] = t[tx][ty + i * 8];
    }
}

// ---------------- bf16 MFMA GEMM: C[M][N] = A[M][K] @ Bt[N][K]^T (+ epilogue) ----
// EPI: 0 = fp32, 1 = fp32 + fp32 residual, 2 = relu^2 -> bf16, 3 = bf16
template <int EPI, int NI>
__global__ __launch_bounds__(256) void gemm_bt(const u16* __restrict__ A,
                                               const u16* __restrict__ Bt,
                                               const float* __restrict__ R,
                                               void* __restrict__ Cout,
                                               int M, int N, int K) {
    __shared__ u16 As[128 * 32];
    __shared__ u16 Bs[NI * 32 * 32];
    int tid = threadIdx.x;
    int w = tid >> 6, lane = tid & 63;
    int quad = lane >> 4, l16 = lane & 15;
    int bm = blockIdx.y * 128;
    int bn = blockIdx.x * (NI * 32);
    int wrow = (w & 1) * 64, wcol = (w >> 1) * (NI * 16);

    f32x4 acc[4][NI];
#pragma unroll
    for (int i = 0; i < 4; ++i)
#pragma unroll
        for (int j = 0; j < NI; ++j) acc[i][j] = (f32x4){0.f, 0.f, 0.f, 0.f};

    int srow = lane >> 2;
    int scol = (lane & 3) * 8;

    for (int k0 = 0; k0 < K; k0 += 32) {
        __syncthreads();
#pragma unroll
        for (int r = 0; r < 2; ++r) {
            int row = r * 64 + w * 16 + srow;
            gl2lds16(A + (size_t)(bm + row) * K + k0 + scol, &As[(r * 64 + w * 16) * 32]);
        }
#pragma unroll
        for (int r = 0; r < NI / 2; ++r) {
            int row = r * 64 + w * 16 + srow;
            gl2lds16(Bt + (size_t)(bn + row) * K + k0 + scol, &Bs[(r * 64 + w * 16) * 32]);
        }
        __syncthreads();

        s16x8 af[4], bf[NI];
#pragma unroll
        for (int mi = 0; mi < 4; ++mi)
            af[mi] = *(const s16x8*)&As[(wrow + mi * 16 + l16) * 32 + quad * 8];
#pragma unroll
        for (int ni = 0; ni < NI; ++ni)
            bf[ni] = *(const s16x8*)&Bs[(wcol + ni * 16 + l16) * 32 + quad * 8];
#pragma unroll
        for (int mi = 0; mi < 4; ++mi)
#pragma unroll
            for (int ni = 0; ni < NI; ++ni)
                acc[mi][ni] = __builtin_amdgcn_mfma_f32_16x16x32_bf16(af[mi], bf[ni],
                                                                      acc[mi][ni], 0, 0, 0);
    }

#pragma unroll
    for (int mi = 0; mi < 4; ++mi) {
#pragma unroll
        for (int rg = 0; rg < 4; ++rg) {
            size_t row = bm + wrow + mi * 16 + quad * 4 + rg;
#pragma unroll
            for (int ni = 0; ni < NI; ++ni) {
                size_t idx = row * N + bn + wcol + ni * 16 + l16;
                float c = acc[mi][ni][rg];
                if (EPI == 0) {
                    ((float*)Cout)[idx] = c;
                } else if (EPI == 1) {
                    ((float*)Cout)[idx] = c + R[idx];
                } else if (EPI == 2) {
                    c = fmaxf(c, 0.f);
                    ((u16*)Cout)[idx] = f2bf(c * c);
                } else {
                    ((u16*)Cout)[idx] = f2bf(c);
                }
            }
        }
    }
}

// ---------------- split-K bf16 MFMA GEMM: fp32 partial per K-slice ---------------
template <int NI>
__global__ __launch_bounds__(256) void gemm_bt_part(const u16* __restrict__ A,
                                                    const u16* __restrict__ Bt,
                                                    float* __restrict__ P,
                                                    int M, int N, int lda,
                                                    int Kc, int kidx0) {
    __shared__ u16 As[128 * 32];
    __shared__ u16 Bs[NI * 32 * 32];
    int tid = threadIdx.x;
    int w = tid >> 6, lane = tid & 63;
    int quad = lane >> 4, l16 = lane & 15;
    int bm = blockIdx.y * 128;
    int bn = blockIdx.x * (NI * 32);
    int wrow = (w & 1) * 64, wcol = (w >> 1) * (NI * 16);
    int kbase = (kidx0 + blockIdx.z) * Kc;

    f32x4 acc[4][NI];
#pragma unroll
    for (int i = 0; i < 4; ++i)
#pragma unroll
        for (int j = 0; j < NI; ++j) acc[i][j] = (f32x4){0.f, 0.f, 0.f, 0.f};

    int srow = lane >> 2;
    int scol = (lane & 3) * 8;

    for (int k0 = 0; k0 < Kc; k0 += 32) {
        __syncthreads();
#pragma unroll
        for (int r = 0; r < 2; ++r) {
            int row = r * 64 + w * 16 + srow;
            gl2lds16(A + (size_t)(bm + row) * lda + kbase + k0 + scol,
                     &As[(r * 64 + w * 16) * 32]);
        }
#pragma unroll
        for (int r = 0; r < NI / 2; ++r) {
            int row = r * 64 + w * 16 + srow;
            gl2lds16(Bt + (size_t)(bn + row) * lda + kbase + k0 + scol,
                     &Bs[(r * 64 + w * 16) * 32]);
        }
        __syncthreads();

        s16x8 af[4], bf[NI];
#pragma unroll
        for (int mi = 0; mi < 4; ++mi)
            af[mi] = *(const s16x8*)&As[(wrow + mi * 16 + l16) * 32 + quad * 8];
#pragma unroll
        for (int ni = 0; ni < NI; ++ni)
            bf[ni] = *(const s16x8*)&Bs[(wcol + ni * 16 + l16) * 32 + quad * 8];
#pragma unroll
        for (int mi = 0; mi < 4; ++mi)
#pragma unroll
            for (int ni = 0; ni < NI; ++ni)
                acc[mi][ni] = __builtin_amdgcn_mfma_f32_16x16x32_bf16(af[mi], bf[ni],
                                                                      acc[mi][ni], 0, 0, 0);
    }

    float* Pz = P + (size_t)blockIdx.z * M * N;
#pragma unroll
    for (int mi = 0; mi < 4; ++mi) {
#pragma unroll
        for (int rg = 0; rg < 4; ++rg) {
            size_t row = bm + wrow + mi * 16 + quad * 4 + rg;
#pragma unroll
            for (int ni = 0; ni < NI; ++ni)
                Pz[row * N + bn + wcol + ni * 16 + l16] = acc[mi][ni][rg];
        }
    }
}

// ---------------- Prep: RoPE + relayout to attention-friendly bf16 buffers -------
// qh pre-scaled by 0.125*log2(e) (exp2-domain softmax downstream).
__global__ __launch_bounds__(256) void rope_prep_kernel(const u16* __restrict__ qkvb,
                                                        const float* __restrict__ cosp,
                                                        const float* __restrict__ sinp,
                                                        u16* __restrict__ qh,
                                                        u16* __restrict__ kh,
                                                        u16* __restrict__ vtp) {
    __shared__ u16 sT[64][72];
    int tc = blockIdx.x, bh = blockIdx.y;
    int h = bh % Hn, b = bh / Hn;
    int t0 = tc * 64;
    int tid = threadIdx.x;

    int r = tid >> 2;
    int c = (tid & 3) * 8;
    int t = t0 + r;
    size_t srow = (size_t)(b * Tn + t) * QKVS + h * HDn;
    float4 c0 = *(const float4*)&cosp[t * D2n + c];
    float4 c1 = *(const float4*)&cosp[t * D2n + c + 4];
    float4 s0 = *(const float4*)&sinp[t * D2n + c];
    float4 s1 = *(const float4*)&sinp[t * D2n + c + 4];
    float cs[8] = {c0.x, c0.y, c0.z, c0.w, c1.x, c1.y, c1.z, c1.w};
    float sn[8] = {s0.x, s0.y, s0.z, s0.w, s1.x, s1.y, s1.z, s1.w};
#pragma unroll
    for (int tens = 0; tens < 2; ++tens) {
        size_t off = srow + tens * Cn;
        float sc = tens ? 1.f : (0.125f * LOG2E);
        ushort4 lo0 = *(const ushort4*)&qkvb[off + c];
        ushort4 lo1 = *(const ushort4*)&qkvb[off + c + 4];
        ushort4 hi0 = *(const ushort4*)&qkvb[off + c + 32];
        ushort4 hi1 = *(const ushort4*)&qkvb[off + c + 36];
        u16 lo[8] = {lo0.x, lo0.y, lo0.z, lo0.w, lo1.x, lo1.y, lo1.z, lo1.w};
        u16 hi[8] = {hi0.x, hi0.y, hi0.z, hi0.w, hi1.x, hi1.y, hi1.z, hi1.w};
        u16 o1[8], o2[8];
#pragma unroll
        for (int j = 0; j < 8; ++j) {
            float x1 = bf2f(lo[j]), x2 = bf2f(hi[j]);
            o1[j] = f2bf((x1 * cs[j] + x2 * sn[j]) * sc);
            o2[j] = f2bf((-x1 * sn[j] + x2 * cs[j]) * sc);
        }
        u16* dst = (tens ? kh : qh) + ((size_t)bh * Tn + t) * HDn;
        *(ushort4*)&dst[c]      = make_ushort4(o1[0], o1[1], o1[2], o1[3]);
        *(ushort4*)&dst[c + 4]  = make_ushort4(o1[4], o1[5], o1[6], o1[7]);
        *(ushort4*)&dst[c + 32] = make_ushort4(o2[0], o2[1], o2[2], o2[3]);
        *(ushort4*)&dst[c + 36] = make_ushort4(o2[4], o2[5], o2[6], o2[7]);
    }

    int r2 = tid >> 2;
    int cc = (tid & 3) * 16;
    size_t vrow = (size_t)(b * Tn + t0 + r2) * QKVS + h * HDn + 2 * Cn;
#pragma unroll
    for (int j = 0; j < 4; ++j)
        *(ushort4*)&sT[r2][cc + j * 4] = *(const ushort4*)&qkvb[vrow + cc + j * 4];
    __syncthreads();
    int d = tid >> 2;
#pragma unroll
    for (int p = 0; p < 2; ++p) {
        int s = (tid & 3) + p * 4;
        int h2 = s >> 2, qq = s & 3;
        u16 e[8];
#pragma unroll
        for (int j = 0; j < 4; ++j) e[j] = sT[32 * h2 + qq * 4 + j][d];
#pragma unroll
        for (int j = 0; j < 4; ++j) e[4 + j] = sT[32 * h2 + 16 + qq * 4 + j][d];
        size_t outb = ((size_t)bh * HDn + d) * Tn + t0 + s * 8;
        *(ushort4*)&vtp[outb]     = make_ushort4(e[0], e[1], e[2], e[3]);
        *(ushort4*)&vtp[outb + 4] = make_ushort4(e[4], e[5], e[6], e[7]);
    }
}

// ---------------- MFMA causal flash attention v5 ---------------------------------
// 128-key chunks, XOR-swizzled unpadded LDS, MAX-FREE exp2 softmax:
// scores are hard-bounded (rmsnorm'd inputs x 0.02-scale weights), so
// p = exp2(s) never over/underflows fp32; O = acc/l is scale-invariant.
__global__ __launch_bounds__(256) void attn_v5_kernel(const u16* __restrict__ qh,
                                                      const u16* __restrict__ kh,
                                                      const u16* __restrict__ vtp,
                                                      u16* __restrict__ y) {
    __shared__ u16 sQ[64 * 64];    // [query][d], swizzled
    __shared__ u16 sK[128 * 64];   // [key][d], swizzled
    __shared__ u16 sV[64 * 128];   // [d][key], swizzled (keys pre-permuted per 64)

    int qt = 31 - (blockIdx.x / 24);  // LPT: heaviest query tiles first
    int bh = blockIdx.x % 24;
    int h = bh % Hn, b = bh / Hn;
    int qbase = qt * 64;
    int tid = threadIdx.x;
    int lane = tid & 63, w = tid >> 6;
    int quad = lane >> 4, l16 = lane & 15;

    const u16* qg = qh + (size_t)bh * Tn * HDn;
    const u16* kg = kh + (size_t)bh * Tn * HDn;
    const u16* vg = vtp + (size_t)bh * HDn * Tn;  // [d][t]

    // stage Q (swizzled): id -> row=id>>3, bd=id&7 ; col = bd ^ (row&7)
#pragma unroll
    for (int i = 0; i < 2; ++i) {
        int id = tid + 256 * i;
        int row = id >> 3, bd = id & 7;
        *(s16x8*)&sQ[row * 64 + ((bd ^ (row & 7)) * 8)] =
            *(const s16x8*)&qg[(size_t)(qbase + row) * HDn + bd * 8];
    }
    __syncthreads();

    const int sw = l16 & 7;
    s16x8 qf0 = *(const s16x8*)&sQ[(w * 16 + l16) * 64 + ((quad ^ sw) * 8)];
    s16x8 qf1 = *(const s16x8*)&sQ[(w * 16 + l16) * 64 + (((quad + 4) ^ sw) * 8)];

    f32x4 acc[4];
#pragma unroll
    for (int i = 0; i < 4; ++i) acc[i] = (f32x4){0.f, 0.f, 0.f, 0.f};
    float l = 0.f;
    const int qloc = w * 16 + l16;

    for (int kbase = 0; kbase <= qbase; kbase += 128) {
        __syncthreads();
#pragma unroll
        for (int i = 0; i < 4; ++i) {
            int id = tid + 256 * i;
            int row = id >> 3, bd = id & 7;
            *(s16x8*)&sK[row * 64 + ((bd ^ (row & 7)) * 8)] =
                *(const s16x8*)&kg[(size_t)(kbase + row) * HDn + bd * 8];
        }
#pragma unroll
        for (int i = 0; i < 4; ++i) {
            int id = tid + 256 * i;
            int row = id >> 4, c = id & 15;
            *(s16x8*)&sV[row * 128 + (((c & 8) | ((c & 7) ^ (row & 7))) * 8)] =
                *(const s16x8*)&vg[(size_t)row * Tn + kbase + c * 8];
        }
        __syncthreads();

        // S^T = K @ Q^T : st[kb] C[key_local=kb*16+quad*4+rg][query=l16]
        f32x4 st[8];
#pragma unroll
        for (int kb = 0; kb < 8; ++kb) {
            int row = kb * 16 + l16;
            s16x8 kf0 = *(const s16x8*)&sK[row * 64 + ((quad ^ sw) * 8)];
            s16x8 kf1 = *(const s16x8*)&sK[row * 64 + (((quad + 4) ^ sw) * 8)];
            f32x4 cfr = (f32x4){0.f, 0.f, 0.f, 0.f};
            cfr = __builtin_amdgcn_mfma_f32_16x16x32_bf16(kf0, qf0, cfr, 0, 0, 0);
            cfr = __builtin_amdgcn_mfma_f32_16x16x32_bf16(kf1, qf1, cfr, 0, 0, 0);
            st[kb] = cfr;
        }

        // causal mask: only the final chunk needs it
        if (kbase + 128 > qbase) {
            int qlim = qbase - kbase + qloc;
#pragma unroll
            for (int kb = 0; kb < 8; ++kb)
#pragma unroll
                for (int rg = 0; rg < 4; ++rg)
                    if (kb * 16 + quad * 4 + rg > qlim) st[kb][rg] = -1e30f;
        }

        // max-free softmax: p = exp2(s), accumulate sum (per query = lane l16)
        float tsum = 0.f;
#pragma unroll
        for (int kb = 0; kb < 8; ++kb) {
#pragma unroll
            for (int rg = 0; rg < 4; ++rg) {
                float p = __builtin_amdgcn_exp2f(st[kb][rg]);
                st[kb][rg] = p;
                tsum += p;
            }
        }
        tsum += __shfl_xor(tsum, 16);
        tsum += __shfl_xor(tsum, 32);
        l += tsum;

        // P fragments (trunc pack); element order matches prep-side V permutation
        union { s16x8 v; unsigned u[4]; } pa[4];
#pragma unroll
        for (int t = 0; t < 4; ++t) {
            pa[t].u[0] = pack2(st[2 * t][0], st[2 * t][1]);
            pa[t].u[1] = pack2(st[2 * t][2], st[2 * t][3]);
            pa[t].u[2] = pack2(st[2 * t + 1][0], st[2 * t + 1][1]);
            pa[t].u[3] = pack2(st[2 * t + 1][2], st[2 * t + 1][3]);
        }

        // O += P @ V : two 64-key halves, pre-permuted V blocks
#pragma unroll
        for (int db = 0; db < 4; ++db) {
            int rr = db * 16 + l16;
#pragma unroll
            for (int hf = 0; hf < 2; ++hf) {
                int c0 = hf * 8 + quad;
                int c1 = hf * 8 + quad + 4;
                s16x8 vf0 = *(const s16x8*)&sV[rr * 128 + (((c0 & 8) | ((c0 & 7) ^ sw)) * 8)];
                s16x8 vf1 = *(const s16x8*)&sV[rr * 128 + (((c1 & 8) | ((c1 & 7) ^ sw)) * 8)];
                acc[db] = __builtin_amdgcn_mfma_f32_16x16x32_bf16(pa[2 * hf].v, vf0, acc[db], 0, 0, 0);
                acc[db] = __builtin_amdgcn_mfma_f32_16x16x32_bf16(pa[2 * hf + 1].v, vf1, acc[db], 0, 0, 0);
            }
        }
    }

    float lq[4];
#pragma unroll
    for (int rg = 0; rg < 4; ++rg) lq[rg] = __shfl(l, quad * 4 + rg);
#pragma unroll
    for (int db = 0; db < 4; ++db) {
#pragma unroll
        for (int rg = 0; rg < 4; ++rg) {
            int row = qbase + w * 16 + quad * 4 + rg;
            y[((size_t)(b * Tn + row) * Hn + h) * HDn + db * 16 + l16] =
                f2bf(acc[db][rg] / lq[rg]);
        }
    }
}

// ---------------- launch ---------------------------------------------------------
extern "C" void kernel_launch(void* const* d_in, const int* in_sizes, int n_in,
                              void* d_out, int out_size, void* d_ws, size_t ws_size,
                              hipStream_t stream) {
    const float* x    = (const float*)d_in[0];
    const float* cosp = (const float*)d_in[1];
    const float* sinp = (const float*)d_in[2];
    const float* wq   = (const float*)d_in[3];
    const float* wk   = (const float*)d_in[4];
    const float* wv   = (const float*)d_in[5];
    const float* wo   = (const float*)d_in[6];
    const float* wfc  = (const float*)d_in[7];
    const float* wpr  = (const float*)d_in[8];
    const float* g1   = (const float*)d_in[9];
    const float* g2   = (const float*)d_in[10];
    float* out = (float*)d_out;

    const size_t S = (size_t)Bn * Tn * Cn;  // 3,145,728 elems
    const size_t MN = S;
    char* W = (char*)d_ws;
    u16* slotA = (u16*)W;                   // [0,2S): h, then h2
    u16* qkvb  = (u16*)(W + 2 * S);         // [2S,8S): qkv bf16
    u16* yh    = (u16*)(W + 2 * S);         // [2S,4S): y bf16 (after prep)
    float* wop = (float*)(W + 4 * S);       // 2 slabs of MN fp32
    u16* fbuf  = (u16*)(W + 4 * S);         // [4S,12S): FF bf16
    u16* qhb   = (u16*)(W + 8 * S);
    u16* khb   = (u16*)(W + 10 * S);
    u16* vtpb  = (u16*)(W + 12 * S);
    float* x1  = (float*)(W + 14 * S);
    u16* wt_qkv = (u16*)(W + 18 * S);
    u16* wt_o   = wt_qkv + (size_t)QKVS * Cn;
    u16* wt_fc  = wt_o + (size_t)Cn * Cn;
    u16* wt_pr  = wt_fc + (size_t)FFn * Cn;
    const size_t WB = ((size_t)QKVS * Cn + (size_t)Cn * Cn + 2 * (size_t)FFn * Cn) * 2;
    float* q0    = (float*)W;                  // wpr slab 0 (reuses [0,4S))
    float* qrest = (float*)(W + 18 * S + WB);  // wpr slabs 1,2

    const int M = Bn * Tn;  // 4096

    transpose_all_kernel<<<6912, 256, 0, stream>>>(wq, wk, wv, wo, wfc, wpr,
                                                   wt_qkv, wt_o, wt_fc, wt_pr);

    rmsnorm_bf16_kernel<<<M, 256, 0, stream>>>(x, g1, slotA);

    // qkv = h @ [wq|wk|wv] -> bf16
    gemm_bt<3, 4><<<dim3(QKVS / 128, M / 128), 256, 0, stream>>>(slotA, wt_qkv, nullptr,
                                                                 qkvb, M, QKVS, Cn);

    rope_prep_kernel<<<dim3(Tn / 64, Bn * Hn), 256, 0, stream>>>(qkvb, cosp, sinp,
                                                                 qhb, khb, vtpb);

    attn_v5_kernel<<<Bn * Hn * (Tn / 64), 256, 0, stream>>>(qhb, khb, vtpb, yh);

    // y @ wo, split-K=2 -> fp32 partials
    gemm_bt_part<2><<<dim3(Cn / 64, M / 128, 2), 256, 0, stream>>>(yh, wt_o, wop,
                                                                   M, Cn, Cn, Cn / 2, 0);
    // x1 = x + p0 + p1 ; h2 = rmsnorm(x1, g2)
    reduce2_rmsnorm_kernel<<<M, 256, 0, stream>>>(wop, wop + MN, x, g2, x1, slotA);

    // f = relu(h2 @ wfc)^2 -> bf16
    gemm_bt<2, 4><<<dim3(FFn / 128, M / 128), 256, 0, stream>>>(slotA, wt_fc, nullptr,
                                                                fbuf, M, FFn, Cn);

    // f @ wpr, split-K=3 (Kc=1024): slab0 -> q0, slabs 1,2 -> qrest
    gemm_bt_part<2><<<dim3(Cn / 64, M / 128, 1), 256, 0, stream>>>(fbuf, wt_pr, q0,
                                                                   M, Cn, FFn, FFn / 3, 0);
    gemm_bt_part<2><<<dim3(Cn / 64, M / 128, 2), 256, 0, stream>>>(fbuf, wt_pr, qrest,
                                                                   M, Cn, FFn, FFn / 3, 1);

    // out = x1 + q0 + qrest0 + qrest1
    reduce_final_kernel<<<(int)(MN / 1024), 256, 0, stream>>>(q0, qrest, x1, out);
}

// Round 10
// 280.724 us; speedup vs baseline: 1.1114x; 1.1114x over previous
//
#include <hip/hip_runtime.h>
#include <hip/hip_bf16.h>
#include <math.h>

// Problem constants
#define Bn 2
#define Tn 2048
#define Cn 768
#define Hn 12
#define HDn 64
#define D2n 32
#define FFn 3072
#define EPSn 1e-5f
#define QKVS (3 * Cn)  // 2304

typedef short s16x8 __attribute__((ext_vector_type(8)));
typedef float f32x4 __attribute__((ext_vector_type(4)));
typedef unsigned short u16;

__device__ __forceinline__ u16 f2bf(float f) {
    union { float f; unsigned u; } v;
    v.f = f;
    unsigned r = (v.u + 0x7fffu + ((v.u >> 16) & 1u)) >> 16;
    return (u16)r;
}
__device__ __forceinline__ float bf2f(u16 u) {
    union { unsigned u; float f; } v;
    v.u = ((unsigned)u) << 16;
    return v.f;
}
__device__ __forceinline__ unsigned pack2(float a, float b) {
    union { float f; unsigned u; } va, vb;
    va.f = a; vb.f = b;
    return (va.u >> 16) | (vb.u & 0xffff0000u);  // trunc-to-bf16 pair
}

__device__ __forceinline__ void gl2lds16(const void* g, void* l) {
    __builtin_amdgcn_global_load_lds((const __attribute__((address_space(1))) void*)g,
                                     (__attribute__((address_space(3))) void*)l,
                                     16, 0, 0);
}

// ---------------- Prologue: 6 weight transposes + rmsnorm1 in ONE launch --------
// blocks [0,6912): W[K][N] fp32 -> Wt[N][K] bf16 32x32 tiles
// blocks [6912,11008): h = rmsnorm(x,g1) row = id-6912
__global__ __launch_bounds__(256) void prologue_kernel(const float* __restrict__ wq,
                                                       const float* __restrict__ wk,
                                                       const float* __restrict__ wv,
                                                       const float* __restrict__ wo,
                                                       const float* __restrict__ wfc,
                                                       const float* __restrict__ wpr,
                                                       u16* __restrict__ wt_qkv,
                                                       u16* __restrict__ wt_o,
                                                       u16* __restrict__ wt_fc,
                                                       u16* __restrict__ wt_pr,
                                                       const float* __restrict__ x,
                                                       const float* __restrict__ g1,
                                                       u16* __restrict__ h) {
    int id = blockIdx.x;
    int tid = threadIdx.x;
    if (id >= 6912) {
        // rmsnorm path
        int row = id - 6912;
        const float* xr = x + (size_t)row * Cn;
        u16* orow = h + (size_t)row * Cn;
        float v[3];
        float ss = 0.f;
#pragma unroll
        for (int i = 0; i < 3; ++i) {
            v[i] = xr[tid + 256 * i];
            ss += v[i] * v[i];
        }
#pragma unroll
        for (int o = 32; o; o >>= 1) ss += __shfl_xor(ss, o);
        __shared__ float red[4];
        int w = tid >> 6;
        if ((tid & 63) == 0) red[w] = ss;
        __syncthreads();
        float tot = red[0] + red[1] + red[2] + red[3];
        float s = rsqrtf(tot / (float)Cn + EPSn);
#pragma unroll
        for (int i = 0; i < 3; ++i) {
            int c = tid + 256 * i;
            orow[c] = f2bf(g1[c] * v[i] * s);
        }
        return;
    }
    const float* W;
    u16* Wt;
    int K, N, lid;
    if (id < 576)       { W = wq;  Wt = wt_qkv;                      K = Cn;  N = Cn;  lid = id; }
    else if (id < 1152) { W = wk;  Wt = wt_qkv + (size_t)Cn * Cn;    K = Cn;  N = Cn;  lid = id - 576; }
    else if (id < 1728) { W = wv;  Wt = wt_qkv + (size_t)2 * Cn * Cn;K = Cn;  N = Cn;  lid = id - 1152; }
    else if (id < 2304) { W = wo;  Wt = wt_o;                        K = Cn;  N = Cn;  lid = id - 1728; }
    else if (id < 4608) { W = wfc; Wt = wt_fc;                       K = Cn;  N = FFn; lid = id - 2304; }
    else                { W = wpr; Wt = wt_pr;                       K = FFn; N = Cn;  lid = id - 4608; }
    int ntx = N / 32;
    int bx = (lid % ntx) * 32;
    int by = (lid / ntx) * 32;

    __shared__ u16 t[32][33];
    int tx = tid & 31, ty = tid >> 5;
#pragma unroll
    for (int i = 0; i < 4; ++i) {
        int kk = by + ty + i * 8;
        t[ty + i * 8][tx] = f2bf(W[(size_t)kk * N + bx + tx]);
    }
    __syncthreads();
#pragma unroll
    for (int i = 0; i < 4; ++i) {
        int n = bx + ty + i * 8;
        Wt[(size_t)n * K + by + tx] = t[tx][ty + i * 8];
    }
}

// ---------------- Fused: x1 = x + p0 + p1 ; h2 = rmsnorm(x1, g) -----------------
__global__ __launch_bounds__(256) void reduce2_rmsnorm_kernel(const float* __restrict__ p0,
                                                              const float* __restrict__ p1,
                                                              const float* __restrict__ x,
                                                              const float* __restrict__ g,
                                                              float* __restrict__ x1,
                                                              u16* __restrict__ h2) {
    int row = blockIdx.x;
    size_t base = (size_t)row * Cn;
    int tid = threadIdx.x;
    float v[3];
    float ss = 0.f;
#pragma unroll
    for (int i = 0; i < 3; ++i) {
        size_t c = base + tid + 256 * i;
        float t = x[c] + p0[c] + p1[c];
        v[i] = t;
        ss += t * t;
    }
#pragma unroll
    for (int o = 32; o; o >>= 1) ss += __shfl_xor(ss, o);
    __shared__ float red[4];
    int w = tid >> 6;
    if ((tid & 63) == 0) red[w] = ss;
    __syncthreads();
    float tot = red[0] + red[1] + red[2] + red[3];
    float s = rsqrtf(tot / (float)Cn + EPSn);
#pragma unroll
    for (int i = 0; i < 3; ++i) {
        int c = tid + 256 * i;
        x1[base + c] = v[i];
        h2[base + c] = f2bf(g[c] * v[i] * s);
    }
}

// ---------------- Final reduce: out = x1 + q0 + qrest[0] + qrest[1] -------------
__global__ __launch_bounds__(256) void reduce_final_kernel(const float* __restrict__ q0,
                                                           const float* __restrict__ qrest,
                                                           const float* __restrict__ x1,
                                                           float* __restrict__ out) {
    const size_t MN = (size_t)Bn * Tn * Cn;
    size_t i = ((size_t)blockIdx.x * 256 + threadIdx.x) * 4;
    float4 a = *(const float4*)&x1[i];
    float4 b = *(const float4*)&q0[i];
    float4 c = *(const float4*)&qrest[i];
    float4 d = *(const float4*)&qrest[MN + i];
    float4 r;
    r.x = a.x + b.x + c.x + d.x;
    r.y = a.y + b.y + c.y + d.y;
    r.z = a.z + b.z + c.z + d.z;
    r.w = a.w + b.w + c.w + d.w;
    *(float4*)&out[i] = r;
}

// ---------------- bf16 MFMA GEMM: C[M][N] = A[M][K] @ Bt[N][K]^T (+ epilogue) ----
// EPI: 0 = fp32, 1 = fp32 + fp32 residual, 2 = relu^2 -> bf16, 3 = bf16
template <int EPI, int NI>
__global__ __launch_bounds__(256) void gemm_bt(const u16* __restrict__ A,
                                               const u16* __restrict__ Bt,
                                               const float* __restrict__ R,
                                               void* __restrict__ Cout,
                                               int M, int N, int K) {
    __shared__ u16 As[128 * 32];
    __shared__ u16 Bs[NI * 32 * 32];
    int tid = threadIdx.x;
    int w = tid >> 6, lane = tid & 63;
    int quad = lane >> 4, l16 = lane & 15;
    int bm = blockIdx.y * 128;
    int bn = blockIdx.x * (NI * 32);
    int wrow = (w & 1) * 64, wcol = (w >> 1) * (NI * 16);

    f32x4 acc[4][NI];
#pragma unroll
    for (int i = 0; i < 4; ++i)
#pragma unroll
        for (int j = 0; j < NI; ++j) acc[i][j] = (f32x4){0.f, 0.f, 0.f, 0.f};

    int srow = lane >> 2;
    int scol = (lane & 3) * 8;

    for (int k0 = 0; k0 < K; k0 += 32) {
        __syncthreads();
#pragma unroll
        for (int r = 0; r < 2; ++r) {
            int row = r * 64 + w * 16 + srow;
            gl2lds16(A + (size_t)(bm + row) * K + k0 + scol, &As[(r * 64 + w * 16) * 32]);
        }
#pragma unroll
        for (int r = 0; r < NI / 2; ++r) {
            int row = r * 64 + w * 16 + srow;
            gl2lds16(Bt + (size_t)(bn + row) * K + k0 + scol, &Bs[(r * 64 + w * 16) * 32]);
        }
        __syncthreads();

        s16x8 af[4], bf[NI];
#pragma unroll
        for (int mi = 0; mi < 4; ++mi)
            af[mi] = *(const s16x8*)&As[(wrow + mi * 16 + l16) * 32 + quad * 8];
#pragma unroll
        for (int ni = 0; ni < NI; ++ni)
            bf[ni] = *(const s16x8*)&Bs[(wcol + ni * 16 + l16) * 32 + quad * 8];
#pragma unroll
        for (int mi = 0; mi < 4; ++mi)
#pragma unroll
            for (int ni = 0; ni < NI; ++ni)
                acc[mi][ni] = __builtin_amdgcn_mfma_f32_16x16x32_bf16(af[mi], bf[ni],
                                                                      acc[mi][ni], 0, 0, 0);
    }

#pragma unroll
    for (int mi = 0; mi < 4; ++mi) {
#pragma unroll
        for (int rg = 0; rg < 4; ++rg) {
            size_t row = bm + wrow + mi * 16 + quad * 4 + rg;
#pragma unroll
            for (int ni = 0; ni < NI; ++ni) {
                size_t idx = row * N + bn + wcol + ni * 16 + l16;
                float c = acc[mi][ni][rg];
                if (EPI == 0) {
                    ((float*)Cout)[idx] = c;
                } else if (EPI == 1) {
                    ((float*)Cout)[idx] = c + R[idx];
                } else if (EPI == 2) {
                    c = fmaxf(c, 0.f);
                    ((u16*)Cout)[idx] = f2bf(c * c);
                } else {
                    ((u16*)Cout)[idx] = f2bf(c);
                }
            }
        }
    }
}

// ---------------- split-K bf16 MFMA GEMM: fp32 partial per K-slice ---------------
// Slab z writes to (z==0 ? P0 : P1 + (z-1)*M*N); K range [z*Kc, (z+1)*Kc).
template <int NI>
__global__ __launch_bounds__(256) void gemm_bt_part(const u16* __restrict__ A,
                                                    const u16* __restrict__ Bt,
                                                    float* __restrict__ P0,
                                                    float* __restrict__ P1,
                                                    int M, int N, int lda, int Kc) {
    __shared__ u16 As[128 * 32];
    __shared__ u16 Bs[NI * 32 * 32];
    int tid = threadIdx.x;
    int w = tid >> 6, lane = tid & 63;
    int quad = lane >> 4, l16 = lane & 15;
    int bm = blockIdx.y * 128;
    int bn = blockIdx.x * (NI * 32);
    int wrow = (w & 1) * 64, wcol = (w >> 1) * (NI * 16);
    int kbase = blockIdx.z * Kc;

    f32x4 acc[4][NI];
#pragma unroll
    for (int i = 0; i < 4; ++i)
#pragma unroll
        for (int j = 0; j < NI; ++j) acc[i][j] = (f32x4){0.f, 0.f, 0.f, 0.f};

    int srow = lane >> 2;
    int scol = (lane & 3) * 8;

    for (int k0 = 0; k0 < Kc; k0 += 32) {
        __syncthreads();
#pragma unroll
        for (int r = 0; r < 2; ++r) {
            int row = r * 64 + w * 16 + srow;
            gl2lds16(A + (size_t)(bm + row) * lda + kbase + k0 + scol,
                     &As[(r * 64 + w * 16) * 32]);
        }
#pragma unroll
        for (int r = 0; r < NI / 2; ++r) {
            int row = r * 64 + w * 16 + srow;
            gl2lds16(Bt + (size_t)(bn + row) * lda + kbase + k0 + scol,
                     &Bs[(r * 64 + w * 16) * 32]);
        }
        __syncthreads();

        s16x8 af[4], bf[NI];
#pragma unroll
        for (int mi = 0; mi < 4; ++mi)
            af[mi] = *(const s16x8*)&As[(wrow + mi * 16 + l16) * 32 + quad * 8];
#pragma unroll
        for (int ni = 0; ni < NI; ++ni)
            bf[ni] = *(const s16x8*)&Bs[(wcol + ni * 16 + l16) * 32 + quad * 8];
#pragma unroll
        for (int mi = 0; mi < 4; ++mi)
#pragma unroll
            for (int ni = 0; ni < NI; ++ni)
                acc[mi][ni] = __builtin_amdgcn_mfma_f32_16x16x32_bf16(af[mi], bf[ni],
                                                                      acc[mi][ni], 0, 0, 0);
    }

    float* Pz = (blockIdx.z == 0) ? P0 : (P1 + (size_t)(blockIdx.z - 1) * M * N);
#pragma unroll
    for (int mi = 0; mi < 4; ++mi) {
#pragma unroll
        for (int rg = 0; rg < 4; ++rg) {
            size_t row = bm + wrow + mi * 16 + quad * 4 + rg;
#pragma unroll
            for (int ni = 0; ni < NI; ++ni)
                Pz[row * N + bn + wcol + ni * 16 + l16] = acc[mi][ni][rg];
        }
    }
}

// ---------------- Prep: RoPE + relayout to attention-friendly bf16 buffers -------
// qh pre-scaled by 0.125 (natural-domain softmax downstream, __expf).
__global__ __launch_bounds__(256) void rope_prep_kernel(const u16* __restrict__ qkvb,
                                                        const float* __restrict__ cosp,
                                                        const float* __restrict__ sinp,
                                                        u16* __restrict__ qh,
                                                        u16* __restrict__ kh,
                                                        u16* __restrict__ vtp) {
    __shared__ u16 sT[64][72];
    int tc = blockIdx.x, bh = blockIdx.y;
    int h = bh % Hn, b = bh / Hn;
    int t0 = tc * 64;
    int tid = threadIdx.x;

    int r = tid >> 2;
    int c = (tid & 3) * 8;
    int t = t0 + r;
    size_t srow = (size_t)(b * Tn + t) * QKVS + h * HDn;
    float4 c0 = *(const float4*)&cosp[t * D2n + c];
    float4 c1 = *(const float4*)&cosp[t * D2n + c + 4];
    float4 s0 = *(const float4*)&sinp[t * D2n + c];
    float4 s1 = *(const float4*)&sinp[t * D2n + c + 4];
    float cs[8] = {c0.x, c0.y, c0.z, c0.w, c1.x, c1.y, c1.z, c1.w};
    float sn[8] = {s0.x, s0.y, s0.z, s0.w, s1.x, s1.y, s1.z, s1.w};
#pragma unroll
    for (int tens = 0; tens < 2; ++tens) {
        size_t off = srow + tens * Cn;
        float sc = tens ? 1.f : 0.125f;
        ushort4 lo0 = *(const ushort4*)&qkvb[off + c];
        ushort4 lo1 = *(const ushort4*)&qkvb[off + c + 4];
        ushort4 hi0 = *(const ushort4*)&qkvb[off + c + 32];
        ushort4 hi1 = *(const ushort4*)&qkvb[off + c + 36];
        u16 lo[8] = {lo0.x, lo0.y, lo0.z, lo0.w, lo1.x, lo1.y, lo1.z, lo1.w};
        u16 hi[8] = {hi0.x, hi0.y, hi0.z, hi0.w, hi1.x, hi1.y, hi1.z, hi1.w};
        u16 o1[8], o2[8];
#pragma unroll
        for (int j = 0; j < 8; ++j) {
            float x1 = bf2f(lo[j]), x2 = bf2f(hi[j]);
            o1[j] = f2bf((x1 * cs[j] + x2 * sn[j]) * sc);
            o2[j] = f2bf((-x1 * sn[j] + x2 * cs[j]) * sc);
        }
        u16* dst = (tens ? kh : qh) + ((size_t)bh * Tn + t) * HDn;
        *(ushort4*)&dst[c]      = make_ushort4(o1[0], o1[1], o1[2], o1[3]);
        *(ushort4*)&dst[c + 4]  = make_ushort4(o1[4], o1[5], o1[6], o1[7]);
        *(ushort4*)&dst[c + 32] = make_ushort4(o2[0], o2[1], o2[2], o2[3]);
        *(ushort4*)&dst[c + 36] = make_ushort4(o2[4], o2[5], o2[6], o2[7]);
    }

    int r2 = tid >> 2;
    int cc = (tid & 3) * 16;
    size_t vrow = (size_t)(b * Tn + t0 + r2) * QKVS + h * HDn + 2 * Cn;
#pragma unroll
    for (int j = 0; j < 4; ++j)
        *(ushort4*)&sT[r2][cc + j * 4] = *(const ushort4*)&qkvb[vrow + cc + j * 4];
    __syncthreads();
    int d = tid >> 2;
#pragma unroll
    for (int p = 0; p < 2; ++p) {
        int s = (tid & 3) + p * 4;
        int h2 = s >> 2, qq = s & 3;
        u16 e[8];
#pragma unroll
        for (int j = 0; j < 4; ++j) e[j] = sT[32 * h2 + qq * 4 + j][d];
#pragma unroll
        for (int j = 0; j < 4; ++j) e[4 + j] = sT[32 * h2 + 16 + qq * 4 + j][d];
        size_t outb = ((size_t)bh * HDn + d) * Tn + t0 + s * 8;
        *(ushort4*)&vtp[outb]     = make_ushort4(e[0], e[1], e[2], e[3]);
        *(ushort4*)&vtp[outb + 4] = make_ushort4(e[4], e[5], e[6], e[7]);
    }
}

// ---------------- MFMA causal flash attention v4b --------------------------------
// v4 structure (measured 43.6 us) with __expf instead of libm exp2f.
__global__ __launch_bounds__(256) void attn_v4b_kernel(const u16* __restrict__ qh,
                                                       const u16* __restrict__ kh,
                                                       const u16* __restrict__ vtp,
                                                       u16* __restrict__ y) {
    __shared__ u16 sQ[64 * 64];    // [query][d], swizzled
    __shared__ u16 sK[128 * 64];   // [key][d], swizzled
    __shared__ u16 sV[64 * 128];   // [d][key], swizzled (keys pre-permuted per 64)

    int qt = 31 - (blockIdx.x / 24);  // LPT: heaviest query tiles first
    int bh = blockIdx.x % 24;
    int h = bh % Hn, b = bh / Hn;
    int qbase = qt * 64;
    int tid = threadIdx.x;
    int lane = tid & 63, w = tid >> 6;
    int quad = lane >> 4, l16 = lane & 15;

    const u16* qg = qh + (size_t)bh * Tn * HDn;
    const u16* kg = kh + (size_t)bh * Tn * HDn;
    const u16* vg = vtp + (size_t)bh * HDn * Tn;  // [d][t]

#pragma unroll
    for (int i = 0; i < 2; ++i) {
        int id = tid + 256 * i;
        int row = id >> 3, bd = id & 7;
        *(s16x8*)&sQ[row * 64 + ((bd ^ (row & 7)) * 8)] =
            *(const s16x8*)&qg[(size_t)(qbase + row) * HDn + bd * 8];
    }
    __syncthreads();

    const int sw = l16 & 7;
    s16x8 qf0 = *(const s16x8*)&sQ[(w * 16 + l16) * 64 + ((quad ^ sw) * 8)];
    s16x8 qf1 = *(const s16x8*)&sQ[(w * 16 + l16) * 64 + (((quad + 4) ^ sw) * 8)];

    f32x4 acc[4];
#pragma unroll
    for (int i = 0; i < 4; ++i) acc[i] = (f32x4){0.f, 0.f, 0.f, 0.f};
    float m = -3e38f, l = 0.f;
    const int qloc = w * 16 + l16;

    for (int kbase = 0; kbase <= qbase; kbase += 128) {
        __syncthreads();
#pragma unroll
        for (int i = 0; i < 4; ++i) {
            int id = tid + 256 * i;
            int row = id >> 3, bd = id & 7;
            *(s16x8*)&sK[row * 64 + ((bd ^ (row & 7)) * 8)] =
                *(const s16x8*)&kg[(size_t)(kbase + row) * HDn + bd * 8];
        }
#pragma unroll
        for (int i = 0; i < 4; ++i) {
            int id = tid + 256 * i;
            int row = id >> 4, c = id & 15;
            *(s16x8*)&sV[row * 128 + (((c & 8) | ((c & 7) ^ (row & 7))) * 8)] =
                *(const s16x8*)&vg[(size_t)row * Tn + kbase + c * 8];
        }
        __syncthreads();

        // S^T = K @ Q^T : st[kb] C[key_local=kb*16+quad*4+rg][query=l16]
        f32x4 st[8];
#pragma unroll
        for (int kb = 0; kb < 8; ++kb) {
            int row = kb * 16 + l16;
            s16x8 kf0 = *(const s16x8*)&sK[row * 64 + ((quad ^ sw) * 8)];
            s16x8 kf1 = *(const s16x8*)&sK[row * 64 + (((quad + 4) ^ sw) * 8)];
            f32x4 cfr = (f32x4){0.f, 0.f, 0.f, 0.f};
            cfr = __builtin_amdgcn_mfma_f32_16x16x32_bf16(kf0, qf0, cfr, 0, 0, 0);
            cfr = __builtin_amdgcn_mfma_f32_16x16x32_bf16(kf1, qf1, cfr, 0, 0, 0);
            st[kb] = cfr;
        }

        if (kbase + 128 > qbase) {
            int qlim = qbase - kbase + qloc;
#pragma unroll
            for (int kb = 0; kb < 8; ++kb)
#pragma unroll
                for (int rg = 0; rg < 4; ++rg)
                    if (kb * 16 + quad * 4 + rg > qlim) st[kb][rg] = -1e30f;
        }

        // online softmax per query (lane l16), __expf
        float mx = -3e38f;
#pragma unroll
        for (int kb = 0; kb < 8; ++kb)
#pragma unroll
            for (int rg = 0; rg < 4; ++rg) mx = fmaxf(mx, st[kb][rg]);
        mx = fmaxf(mx, __shfl_xor(mx, 16));
        mx = fmaxf(mx, __shfl_xor(mx, 32));
        float mnew = fmaxf(m, mx);
        float alpha = __expf(m - mnew);
        m = mnew;
        float tsum = 0.f;
#pragma unroll
        for (int kb = 0; kb < 8; ++kb) {
#pragma unroll
            for (int rg = 0; rg < 4; ++rg) {
                float p = __expf(st[kb][rg] - mnew);
                st[kb][rg] = p;
                tsum += p;
            }
        }
        tsum += __shfl_xor(tsum, 16);
        tsum += __shfl_xor(tsum, 32);
        l = l * alpha + tsum;

        float aq[4];
#pragma unroll
        for (int rg = 0; rg < 4; ++rg) aq[rg] = __shfl(alpha, quad * 4 + rg);
#pragma unroll
        for (int db = 0; db < 4; ++db)
#pragma unroll
            for (int rg = 0; rg < 4; ++rg) acc[db][rg] *= aq[rg];

        union { s16x8 v; unsigned u[4]; } pa[4];
#pragma unroll
        for (int t = 0; t < 4; ++t) {
            pa[t].u[0] = pack2(st[2 * t][0], st[2 * t][1]);
            pa[t].u[1] = pack2(st[2 * t][2], st[2 * t][3]);
            pa[t].u[2] = pack2(st[2 * t + 1][0], st[2 * t + 1][1]);
            pa[t].u[3] = pack2(st[2 * t + 1][2], st[2 * t + 1][3]);
        }

#pragma unroll
        for (int db = 0; db < 4; ++db) {
            int rr = db * 16 + l16;
#pragma unroll
            for (int hf = 0; hf < 2; ++hf) {
                int c0 = hf * 8 + quad;
                int c1 = hf * 8 + quad + 4;
                s16x8 vf0 = *(const s16x8*)&sV[rr * 128 + (((c0 & 8) | ((c0 & 7) ^ sw)) * 8)];
                s16x8 vf1 = *(const s16x8*)&sV[rr * 128 + (((c1 & 8) | ((c1 & 7) ^ sw)) * 8)];
                acc[db] = __builtin_amdgcn_mfma_f32_16x16x32_bf16(pa[2 * hf].v, vf0, acc[db], 0, 0, 0);
                acc[db] = __builtin_amdgcn_mfma_f32_16x16x32_bf16(pa[2 * hf + 1].v, vf1, acc[db], 0, 0, 0);
            }
        }
    }

    float lq[4];
#pragma unroll
    for (int rg = 0; rg < 4; ++rg) lq[rg] = __shfl(l, quad * 4 + rg);
#pragma unroll
    for (int db = 0; db < 4; ++db) {
#pragma unroll
        for (int rg = 0; rg < 4; ++rg) {
            int row = qbase + w * 16 + quad * 4 + rg;
            y[((size_t)(b * Tn + row) * Hn + h) * HDn + db * 16 + l16] =
                f2bf(acc[db][rg] / lq[rg]);
        }
    }
}

// ---------------- launch ---------------------------------------------------------
extern "C" void kernel_launch(void* const* d_in, const int* in_sizes, int n_in,
                              void* d_out, int out_size, void* d_ws, size_t ws_size,
                              hipStream_t stream) {
    const float* x    = (const float*)d_in[0];
    const float* cosp = (const float*)d_in[1];
    const float* sinp = (const float*)d_in[2];
    const float* wq   = (const float*)d_in[3];
    const float* wk   = (const float*)d_in[4];
    const float* wv   = (const float*)d_in[5];
    const float* wo   = (const float*)d_in[6];
    const float* wfc  = (const float*)d_in[7];
    const float* wpr  = (const float*)d_in[8];
    const float* g1   = (const float*)d_in[9];
    const float* g2   = (const float*)d_in[10];
    float* out = (float*)d_out;

    const size_t S = (size_t)Bn * Tn * Cn;  // 3,145,728 elems
    const size_t MN = S;
    char* W = (char*)d_ws;
    u16* slotA = (u16*)W;                   // [0,2S): h, then h2
    u16* qkvb  = (u16*)(W + 2 * S);         // [2S,8S): qkv bf16
    u16* yh    = (u16*)(W + 2 * S);         // [2S,4S): y bf16 (after prep)
    float* wop = (float*)(W + 4 * S);       // 2 slabs of MN fp32
    u16* fbuf  = (u16*)(W + 4 * S);         // [4S,12S): FF bf16
    u16* qhb   = (u16*)(W + 8 * S);
    u16* khb   = (u16*)(W + 10 * S);
    u16* vtpb  = (u16*)(W + 12 * S);
    float* x1  = (float*)(W + 14 * S);
    u16* wt_qkv = (u16*)(W + 18 * S);
    u16* wt_o   = wt_qkv + (size_t)QKVS * Cn;
    u16* wt_fc  = wt_o + (size_t)Cn * Cn;
    u16* wt_pr  = wt_fc + (size_t)FFn * Cn;
    const size_t WB = ((size_t)QKVS * Cn + (size_t)Cn * Cn + 2 * (size_t)FFn * Cn) * 2;
    float* q0    = (float*)W;                  // wpr slab 0 (reuses [0,4S))
    float* qrest = (float*)(W + 18 * S + WB);  // wpr slabs 1,2

    const int M = Bn * Tn;  // 4096

    // transposes + rmsnorm1 in one launch
    prologue_kernel<<<6912 + M, 256, 0, stream>>>(wq, wk, wv, wo, wfc, wpr,
                                                  wt_qkv, wt_o, wt_fc, wt_pr,
                                                  x, g1, slotA);

    // qkv = h @ [wq|wk|wv] -> bf16
    gemm_bt<3, 4><<<dim3(QKVS / 128, M / 128), 256, 0, stream>>>(slotA, wt_qkv, nullptr,
                                                                 qkvb, M, QKVS, Cn);

    rope_prep_kernel<<<dim3(Tn / 64, Bn * Hn), 256, 0, stream>>>(qkvb, cosp, sinp,
                                                                 qhb, khb, vtpb);

    attn_v4b_kernel<<<Bn * Hn * (Tn / 64), 256, 0, stream>>>(qhb, khb, vtpb, yh);

    // y @ wo, split-K=2 -> fp32 partials (slabs contiguous: P0=wop, P1=wop+MN)
    gemm_bt_part<2><<<dim3(Cn / 64, M / 128, 2), 256, 0, stream>>>(yh, wt_o, wop, wop + MN,
                                                                   M, Cn, Cn, Cn / 2);
    // x1 = x + p0 + p1 ; h2 = rmsnorm(x1, g2)
    reduce2_rmsnorm_kernel<<<M, 256, 0, stream>>>(wop, wop + MN, x, g2, x1, slotA);

    // f = relu(h2 @ wfc)^2 -> bf16
    gemm_bt<2, 4><<<dim3(FFn / 128, M / 128), 256, 0, stream>>>(slotA, wt_fc, nullptr,
                                                                fbuf, M, FFn, Cn);

    // f @ wpr, split-K=3 (Kc=1024) in ONE launch: z=0 -> q0, z=1,2 -> qrest
    gemm_bt_part<2><<<dim3(Cn / 64, M / 128, 3), 256, 0, stream>>>(fbuf, wt_pr, q0, qrest,
                                                                   M, Cn, FFn, FFn / 3);

    // out = x1 + q0 + qrest0 + qrest1
    reduce_final_kernel<<<(int)(MN / 1024), 256, 0, stream>>>(q0, qrest, x1, out);
}

// Round 11
// 277.750 us; speedup vs baseline: 1.1233x; 1.0107x over previous
//
#include <hip/hip_runtime.h>
#include <hip/hip_bf16.h>
#include <math.h>

// Problem constants
#define Bn 2
#define Tn 2048
#define Cn 768
#define Hn 12
#define HDn 64
#define D2n 32
#define FFn 3072
#define EPSn 1e-5f
#define QKVS (3 * Cn)  // 2304

typedef short s16x8 __attribute__((ext_vector_type(8)));
typedef float f32x4 __attribute__((ext_vector_type(4)));
typedef unsigned short u16;

__device__ __forceinline__ u16 f2bf(float f) {
    union { float f; unsigned u; } v;
    v.f = f;
    unsigned r = (v.u + 0x7fffu + ((v.u >> 16) & 1u)) >> 16;
    return (u16)r;
}
__device__ __forceinline__ float bf2f(u16 u) {
    union { unsigned u; float f; } v;
    v.u = ((unsigned)u) << 16;
    return v.f;
}
__device__ __forceinline__ unsigned pack2(float a, float b) {
    union { float f; unsigned u; } va, vb;
    va.f = a; vb.f = b;
    return (va.u >> 16) | (vb.u & 0xffff0000u);  // trunc-to-bf16 pair
}

__device__ __forceinline__ void gl2lds16(const void* g, void* l) {
    __builtin_amdgcn_global_load_lds((const __attribute__((address_space(1))) void*)g,
                                     (__attribute__((address_space(3))) void*)l,
                                     16, 0, 0);
}

// ---------------- Prologue: 6 weight transposes + rmsnorm1 in ONE launch --------
__global__ __launch_bounds__(256) void prologue_kernel(const float* __restrict__ wq,
                                                       const float* __restrict__ wk,
                                                       const float* __restrict__ wv,
                                                       const float* __restrict__ wo,
                                                       const float* __restrict__ wfc,
                                                       const float* __restrict__ wpr,
                                                       u16* __restrict__ wt_qkv,
                                                       u16* __restrict__ wt_o,
                                                       u16* __restrict__ wt_fc,
                                                       u16* __restrict__ wt_pr,
                                                       const float* __restrict__ x,
                                                       const float* __restrict__ g1,
                                                       u16* __restrict__ h) {
    int id = blockIdx.x;
    int tid = threadIdx.x;
    if (id >= 6912) {
        int row = id - 6912;
        const float* xr = x + (size_t)row * Cn;
        u16* orow = h + (size_t)row * Cn;
        float v[3];
        float ss = 0.f;
#pragma unroll
        for (int i = 0; i < 3; ++i) {
            v[i] = xr[tid + 256 * i];
            ss += v[i] * v[i];
        }
#pragma unroll
        for (int o = 32; o; o >>= 1) ss += __shfl_xor(ss, o);
        __shared__ float red[4];
        int w = tid >> 6;
        if ((tid & 63) == 0) red[w] = ss;
        __syncthreads();
        float tot = red[0] + red[1] + red[2] + red[3];
        float s = rsqrtf(tot / (float)Cn + EPSn);
#pragma unroll
        for (int i = 0; i < 3; ++i) {
            int c = tid + 256 * i;
            orow[c] = f2bf(g1[c] * v[i] * s);
        }
        return;
    }
    const float* W;
    u16* Wt;
    int K, N, lid;
    if (id < 576)       { W = wq;  Wt = wt_qkv;                      K = Cn;  N = Cn;  lid = id; }
    else if (id < 1152) { W = wk;  Wt = wt_qkv + (size_t)Cn * Cn;    K = Cn;  N = Cn;  lid = id - 576; }
    else if (id < 1728) { W = wv;  Wt = wt_qkv + (size_t)2 * Cn * Cn;K = Cn;  N = Cn;  lid = id - 1152; }
    else if (id < 2304) { W = wo;  Wt = wt_o;                        K = Cn;  N = Cn;  lid = id - 1728; }
    else if (id < 4608) { W = wfc; Wt = wt_fc;                       K = Cn;  N = FFn; lid = id - 2304; }
    else                { W = wpr; Wt = wt_pr;                       K = FFn; N = Cn;  lid = id - 4608; }
    int ntx = N / 32;
    int bx = (lid % ntx) * 32;
    int by = (lid / ntx) * 32;

    __shared__ u16 t[32][33];
    int tx = tid & 31, ty = tid >> 5;
#pragma unroll
    for (int i = 0; i < 4; ++i) {
        int kk = by + ty + i * 8;
        t[ty + i * 8][tx] = f2bf(W[(size_t)kk * N + bx + tx]);
    }
    __syncthreads();
#pragma unroll
    for (int i = 0; i < 4; ++i) {
        int n = bx + ty + i * 8;
        Wt[(size_t)n * K + by + tx] = t[tx][ty + i * 8];
    }
}

// ---------------- Fused: x1 = x + p0 + p1 ; h2 = rmsnorm(x1, g) -----------------
__global__ __launch_bounds__(256) void reduce2_rmsnorm_kernel(const float* __restrict__ p0,
                                                              const float* __restrict__ p1,
                                                              const float* __restrict__ x,
                                                              const float* __restrict__ g,
                                                              float* __restrict__ x1,
                                                              u16* __restrict__ h2) {
    int row = blockIdx.x;
    size_t base = (size_t)row * Cn;
    int tid = threadIdx.x;
    float v[3];
    float ss = 0.f;
#pragma unroll
    for (int i = 0; i < 3; ++i) {
        size_t c = base + tid + 256 * i;
        float t = x[c] + p0[c] + p1[c];
        v[i] = t;
        ss += t * t;
    }
#pragma unroll
    for (int o = 32; o; o >>= 1) ss += __shfl_xor(ss, o);
    __shared__ float red[4];
    int w = tid >> 6;
    if ((tid & 63) == 0) red[w] = ss;
    __syncthreads();
    float tot = red[0] + red[1] + red[2] + red[3];
    float s = rsqrtf(tot / (float)Cn + EPSn);
#pragma unroll
    for (int i = 0; i < 3; ++i) {
        int c = tid + 256 * i;
        x1[base + c] = v[i];
        h2[base + c] = f2bf(g[c] * v[i] * s);
    }
}

// ---------------- Final reduce: out = x1 + q0 + qrest[0] + qrest[1] -------------
__global__ __launch_bounds__(256) void reduce_final_kernel(const float* __restrict__ q0,
                                                           const float* __restrict__ qrest,
                                                           const float* __restrict__ x1,
                                                           float* __restrict__ out) {
    const size_t MN = (size_t)Bn * Tn * Cn;
    size_t i = ((size_t)blockIdx.x * 256 + threadIdx.x) * 4;
    float4 a = *(const float4*)&x1[i];
    float4 b = *(const float4*)&q0[i];
    float4 c = *(const float4*)&qrest[i];
    float4 d = *(const float4*)&qrest[MN + i];
    float4 r;
    r.x = a.x + b.x + c.x + d.x;
    r.y = a.y + b.y + c.y + d.y;
    r.z = a.z + b.z + c.z + d.z;
    r.w = a.w + b.w + c.w + d.w;
    *(float4*)&out[i] = r;
}

// ---------------- bf16 MFMA GEMM: C[M][N] = A[M][K] @ Bt[N][K]^T (+ epilogue) ----
// EPI: 0 = fp32, 1 = fp32 + fp32 residual, 2 = relu^2 -> bf16, 3 = bf16
template <int EPI, int NI>
__global__ __launch_bounds__(256) void gemm_bt(const u16* __restrict__ A,
                                               const u16* __restrict__ Bt,
                                               const float* __restrict__ R,
                                               void* __restrict__ Cout,
                                               int M, int N, int K) {
    __shared__ u16 As[128 * 32];
    __shared__ u16 Bs[NI * 32 * 32];
    int tid = threadIdx.x;
    int w = tid >> 6, lane = tid & 63;
    int quad = lane >> 4, l16 = lane & 15;
    int bm = blockIdx.y * 128;
    int bn = blockIdx.x * (NI * 32);
    int wrow = (w & 1) * 64, wcol = (w >> 1) * (NI * 16);

    f32x4 acc[4][NI];
#pragma unroll
    for (int i = 0; i < 4; ++i)
#pragma unroll
        for (int j = 0; j < NI; ++j) acc[i][j] = (f32x4){0.f, 0.f, 0.f, 0.f};

    int srow = lane >> 2;
    int scol = (lane & 3) * 8;

    for (int k0 = 0; k0 < K; k0 += 32) {
        __syncthreads();
#pragma unroll
        for (int r = 0; r < 2; ++r) {
            int row = r * 64 + w * 16 + srow;
            gl2lds16(A + (size_t)(bm + row) * K + k0 + scol, &As[(r * 64 + w * 16) * 32]);
        }
#pragma unroll
        for (int r = 0; r < NI / 2; ++r) {
            int row = r * 64 + w * 16 + srow;
            gl2lds16(Bt + (size_t)(bn + row) * K + k0 + scol, &Bs[(r * 64 + w * 16) * 32]);
        }
        __syncthreads();

        s16x8 af[4], bf[NI];
#pragma unroll
        for (int mi = 0; mi < 4; ++mi)
            af[mi] = *(const s16x8*)&As[(wrow + mi * 16 + l16) * 32 + quad * 8];
#pragma unroll
        for (int ni = 0; ni < NI; ++ni)
            bf[ni] = *(const s16x8*)&Bs[(wcol + ni * 16 + l16) * 32 + quad * 8];
#pragma unroll
        for (int mi = 0; mi < 4; ++mi)
#pragma unroll
            for (int ni = 0; ni < NI; ++ni)
                acc[mi][ni] = __builtin_amdgcn_mfma_f32_16x16x32_bf16(af[mi], bf[ni],
                                                                      acc[mi][ni], 0, 0, 0);
    }

#pragma unroll
    for (int mi = 0; mi < 4; ++mi) {
#pragma unroll
        for (int rg = 0; rg < 4; ++rg) {
            size_t row = bm + wrow + mi * 16 + quad * 4 + rg;
#pragma unroll
            for (int ni = 0; ni < NI; ++ni) {
                size_t idx = row * N + bn + wcol + ni * 16 + l16;
                float c = acc[mi][ni][rg];
                if (EPI == 0) {
                    ((float*)Cout)[idx] = c;
                } else if (EPI == 1) {
                    ((float*)Cout)[idx] = c + R[idx];
                } else if (EPI == 2) {
                    c = fmaxf(c, 0.f);
                    ((u16*)Cout)[idx] = f2bf(c * c);
                } else {
                    ((u16*)Cout)[idx] = f2bf(c);
                }
            }
        }
    }
}

// ---------------- split-K bf16 MFMA GEMM: fp32 partial per K-slice ---------------
// Slab z writes to (z==0 ? P0 : P1 + (z-1)*M*N); K range [z*Kc, (z+1)*Kc).
template <int NI>
__global__ __launch_bounds__(256) void gemm_bt_part(const u16* __restrict__ A,
                                                    const u16* __restrict__ Bt,
                                                    float* __restrict__ P0,
                                                    float* __restrict__ P1,
                                                    int M, int N, int lda, int Kc) {
    __shared__ u16 As[128 * 32];
    __shared__ u16 Bs[NI * 32 * 32];
    int tid = threadIdx.x;
    int w = tid >> 6, lane = tid & 63;
    int quad = lane >> 4, l16 = lane & 15;
    int bm = blockIdx.y * 128;
    int bn = blockIdx.x * (NI * 32);
    int wrow = (w & 1) * 64, wcol = (w >> 1) * (NI * 16);
    int kbase = blockIdx.z * Kc;

    f32x4 acc[4][NI];
#pragma unroll
    for (int i = 0; i < 4; ++i)
#pragma unroll
        for (int j = 0; j < NI; ++j) acc[i][j] = (f32x4){0.f, 0.f, 0.f, 0.f};

    int srow = lane >> 2;
    int scol = (lane & 3) * 8;

    for (int k0 = 0; k0 < Kc; k0 += 32) {
        __syncthreads();
#pragma unroll
        for (int r = 0; r < 2; ++r) {
            int row = r * 64 + w * 16 + srow;
            gl2lds16(A + (size_t)(bm + row) * lda + kbase + k0 + scol,
                     &As[(r * 64 + w * 16) * 32]);
        }
#pragma unroll
        for (int r = 0; r < NI / 2; ++r) {
            int row = r * 64 + w * 16 + srow;
            gl2lds16(Bt + (size_t)(bn + row) * lda + kbase + k0 + scol,
                     &Bs[(r * 64 + w * 16) * 32]);
        }
        __syncthreads();

        s16x8 af[4], bf[NI];
#pragma unroll
        for (int mi = 0; mi < 4; ++mi)
            af[mi] = *(const s16x8*)&As[(wrow + mi * 16 + l16) * 32 + quad * 8];
#pragma unroll
        for (int ni = 0; ni < NI; ++ni)
            bf[ni] = *(const s16x8*)&Bs[(wcol + ni * 16 + l16) * 32 + quad * 8];
#pragma unroll
        for (int mi = 0; mi < 4; ++mi)
#pragma unroll
            for (int ni = 0; ni < NI; ++ni)
                acc[mi][ni] = __builtin_amdgcn_mfma_f32_16x16x32_bf16(af[mi], bf[ni],
                                                                      acc[mi][ni], 0, 0, 0);
    }

    float* Pz = (blockIdx.z == 0) ? P0 : (P1 + (size_t)(blockIdx.z - 1) * M * N);
#pragma unroll
    for (int mi = 0; mi < 4; ++mi) {
#pragma unroll
        for (int rg = 0; rg < 4; ++rg) {
            size_t row = bm + wrow + mi * 16 + quad * 4 + rg;
#pragma unroll
            for (int ni = 0; ni < NI; ++ni)
                Pz[row * N + bn + wcol + ni * 16 + l16] = acc[mi][ni][rg];
        }
    }
}

// ---------------- Prep: RoPE + relayout to attention-friendly bf16 buffers -------
// qh pre-scaled by 0.125 (natural-domain softmax downstream, __expf).
__global__ __launch_bounds__(256) void rope_prep_kernel(const u16* __restrict__ qkvb,
                                                        const float* __restrict__ cosp,
                                                        const float* __restrict__ sinp,
                                                        u16* __restrict__ qh,
                                                        u16* __restrict__ kh,
                                                        u16* __restrict__ vtp) {
    __shared__ u16 sT[64][72];
    int tc = blockIdx.x, bh = blockIdx.y;
    int h = bh % Hn, b = bh / Hn;
    int t0 = tc * 64;
    int tid = threadIdx.x;

    int r = tid >> 2;
    int c = (tid & 3) * 8;
    int t = t0 + r;
    size_t srow = (size_t)(b * Tn + t) * QKVS + h * HDn;
    float4 c0 = *(const float4*)&cosp[t * D2n + c];
    float4 c1 = *(const float4*)&cosp[t * D2n + c + 4];
    float4 s0 = *(const float4*)&sinp[t * D2n + c];
    float4 s1 = *(const float4*)&sinp[t * D2n + c + 4];
    float cs[8] = {c0.x, c0.y, c0.z, c0.w, c1.x, c1.y, c1.z, c1.w};
    float sn[8] = {s0.x, s0.y, s0.z, s0.w, s1.x, s1.y, s1.z, s1.w};
#pragma unroll
    for (int tens = 0; tens < 2; ++tens) {
        size_t off = srow + tens * Cn;
        float sc = tens ? 1.f : 0.125f;
        ushort4 lo0 = *(const ushort4*)&qkvb[off + c];
        ushort4 lo1 = *(const ushort4*)&qkvb[off + c + 4];
        ushort4 hi0 = *(const ushort4*)&qkvb[off + c + 32];
        ushort4 hi1 = *(const ushort4*)&qkvb[off + c + 36];
        u16 lo[8] = {lo0.x, lo0.y, lo0.z, lo0.w, lo1.x, lo1.y, lo1.z, lo1.w};
        u16 hi[8] = {hi0.x, hi0.y, hi0.z, hi0.w, hi1.x, hi1.y, hi1.z, hi1.w};
        u16 o1[8], o2[8];
#pragma unroll
        for (int j = 0; j < 8; ++j) {
            float x1 = bf2f(lo[j]), x2 = bf2f(hi[j]);
            o1[j] = f2bf((x1 * cs[j] + x2 * sn[j]) * sc);
            o2[j] = f2bf((-x1 * sn[j] + x2 * cs[j]) * sc);
        }
        u16* dst = (tens ? kh : qh) + ((size_t)bh * Tn + t) * HDn;
        *(ushort4*)&dst[c]      = make_ushort4(o1[0], o1[1], o1[2], o1[3]);
        *(ushort4*)&dst[c + 4]  = make_ushort4(o1[4], o1[5], o1[6], o1[7]);
        *(ushort4*)&dst[c + 32] = make_ushort4(o2[0], o2[1], o2[2], o2[3]);
        *(ushort4*)&dst[c + 36] = make_ushort4(o2[4], o2[5], o2[6], o2[7]);
    }

    int r2 = tid >> 2;
    int cc = (tid & 3) * 16;
    size_t vrow = (size_t)(b * Tn + t0 + r2) * QKVS + h * HDn + 2 * Cn;
#pragma unroll
    for (int j = 0; j < 4; ++j)
        *(ushort4*)&sT[r2][cc + j * 4] = *(const ushort4*)&qkvb[vrow + cc + j * 4];
    __syncthreads();
    int d = tid >> 2;
#pragma unroll
    for (int p = 0; p < 2; ++p) {
        int s = (tid & 3) + p * 4;
        int h2 = s >> 2, qq = s & 3;
        u16 e[8];
#pragma unroll
        for (int j = 0; j < 4; ++j) e[j] = sT[32 * h2 + qq * 4 + j][d];
#pragma unroll
        for (int j = 0; j < 4; ++j) e[4 + j] = sT[32 * h2 + 16 + qq * 4 + j][d];
        size_t outb = ((size_t)bh * HDn + d) * Tn + t0 + s * 8;
        *(ushort4*)&vtp[outb]     = make_ushort4(e[0], e[1], e[2], e[3]);
        *(ushort4*)&vtp[outb + 4] = make_ushort4(e[4], e[5], e[6], e[7]);
    }
}

// ---------------- MFMA causal flash attention v4b --------------------------------
__global__ __launch_bounds__(256) void attn_v4b_kernel(const u16* __restrict__ qh,
                                                       const u16* __restrict__ kh,
                                                       const u16* __restrict__ vtp,
                                                       u16* __restrict__ y) {
    __shared__ u16 sQ[64 * 64];    // [query][d], swizzled
    __shared__ u16 sK[128 * 64];   // [key][d], swizzled
    __shared__ u16 sV[64 * 128];   // [d][key], swizzled (keys pre-permuted per 64)

    int qt = 31 - (blockIdx.x / 24);  // LPT: heaviest query tiles first
    int bh = blockIdx.x % 24;
    int h = bh % Hn, b = bh / Hn;
    int qbase = qt * 64;
    int tid = threadIdx.x;
    int lane = tid & 63, w = tid >> 6;
    int quad = lane >> 4, l16 = lane & 15;

    const u16* qg = qh + (size_t)bh * Tn * HDn;
    const u16* kg = kh + (size_t)bh * Tn * HDn;
    const u16* vg = vtp + (size_t)bh * HDn * Tn;  // [d][t]

#pragma unroll
    for (int i = 0; i < 2; ++i) {
        int id = tid + 256 * i;
        int row = id >> 3, bd = id & 7;
        *(s16x8*)&sQ[row * 64 + ((bd ^ (row & 7)) * 8)] =
            *(const s16x8*)&qg[(size_t)(qbase + row) * HDn + bd * 8];
    }
    __syncthreads();

    const int sw = l16 & 7;
    s16x8 qf0 = *(const s16x8*)&sQ[(w * 16 + l16) * 64 + ((quad ^ sw) * 8)];
    s16x8 qf1 = *(const s16x8*)&sQ[(w * 16 + l16) * 64 + (((quad + 4) ^ sw) * 8)];

    f32x4 acc[4];
#pragma unroll
    for (int i = 0; i < 4; ++i) acc[i] = (f32x4){0.f, 0.f, 0.f, 0.f};
    float m = -3e38f, l = 0.f;
    const int qloc = w * 16 + l16;

    for (int kbase = 0; kbase <= qbase; kbase += 128) {
        __syncthreads();
#pragma unroll
        for (int i = 0; i < 4; ++i) {
            int id = tid + 256 * i;
            int row = id >> 3, bd = id & 7;
            *(s16x8*)&sK[row * 64 + ((bd ^ (row & 7)) * 8)] =
                *(const s16x8*)&kg[(size_t)(kbase + row) * HDn + bd * 8];
        }
#pragma unroll
        for (int i = 0; i < 4; ++i) {
            int id = tid + 256 * i;
            int row = id >> 4, c = id & 15;
            *(s16x8*)&sV[row * 128 + (((c & 8) | ((c & 7) ^ (row & 7))) * 8)] =
                *(const s16x8*)&vg[(size_t)row * Tn + kbase + c * 8];
        }
        __syncthreads();

        // S^T = K @ Q^T : st[kb] C[key_local=kb*16+quad*4+rg][query=l16]
        f32x4 st[8];
#pragma unroll
        for (int kb = 0; kb < 8; ++kb) {
            int row = kb * 16 + l16;
            s16x8 kf0 = *(const s16x8*)&sK[row * 64 + ((quad ^ sw) * 8)];
            s16x8 kf1 = *(const s16x8*)&sK[row * 64 + (((quad + 4) ^ sw) * 8)];
            f32x4 cfr = (f32x4){0.f, 0.f, 0.f, 0.f};
            cfr = __builtin_amdgcn_mfma_f32_16x16x32_bf16(kf0, qf0, cfr, 0, 0, 0);
            cfr = __builtin_amdgcn_mfma_f32_16x16x32_bf16(kf1, qf1, cfr, 0, 0, 0);
            st[kb] = cfr;
        }

        if (kbase + 128 > qbase) {
            int qlim = qbase - kbase + qloc;
#pragma unroll
            for (int kb = 0; kb < 8; ++kb)
#pragma unroll
                for (int rg = 0; rg < 4; ++rg)
                    if (kb * 16 + quad * 4 + rg > qlim) st[kb][rg] = -1e30f;
        }

        // online softmax per query (lane l16), __expf
        float mx = -3e38f;
#pragma unroll
        for (int kb = 0; kb < 8; ++kb)
#pragma unroll
            for (int rg = 0; rg < 4; ++rg) mx = fmaxf(mx, st[kb][rg]);
        mx = fmaxf(mx, __shfl_xor(mx, 16));
        mx = fmaxf(mx, __shfl_xor(mx, 32));
        float mnew = fmaxf(m, mx);
        float alpha = __expf(m - mnew);
        m = mnew;
        float tsum = 0.f;
#pragma unroll
        for (int kb = 0; kb < 8; ++kb) {
#pragma unroll
            for (int rg = 0; rg < 4; ++rg) {
                float p = __expf(st[kb][rg] - mnew);
                st[kb][rg] = p;
                tsum += p;
            }
        }
        tsum += __shfl_xor(tsum, 16);
        tsum += __shfl_xor(tsum, 32);
        l = l * alpha + tsum;

        float aq[4];
#pragma unroll
        for (int rg = 0; rg < 4; ++rg) aq[rg] = __shfl(alpha, quad * 4 + rg);
#pragma unroll
        for (int db = 0; db < 4; ++db)
#pragma unroll
            for (int rg = 0; rg < 4; ++rg) acc[db][rg] *= aq[rg];

        union { s16x8 v; unsigned u[4]; } pa[4];
#pragma unroll
        for (int t = 0; t < 4; ++t) {
            pa[t].u[0] = pack2(st[2 * t][0], st[2 * t][1]);
            pa[t].u[1] = pack2(st[2 * t][2], st[2 * t][3]);
            pa[t].u[2] = pack2(st[2 * t + 1][0], st[2 * t + 1][1]);
            pa[t].u[3] = pack2(st[2 * t + 1][2], st[2 * t + 1][3]);
        }

#pragma unroll
        for (int db = 0; db < 4; ++db) {
            int rr = db * 16 + l16;
#pragma unroll
            for (int hf = 0; hf < 2; ++hf) {
                int c0 = hf * 8 + quad;
                int c1 = hf * 8 + quad + 4;
                s16x8 vf0 = *(const s16x8*)&sV[rr * 128 + (((c0 & 8) | ((c0 & 7) ^ sw)) * 8)];
                s16x8 vf1 = *(const s16x8*)&sV[rr * 128 + (((c1 & 8) | ((c1 & 7) ^ sw)) * 8)];
                acc[db] = __builtin_amdgcn_mfma_f32_16x16x32_bf16(pa[2 * hf].v, vf0, acc[db], 0, 0, 0);
                acc[db] = __builtin_amdgcn_mfma_f32_16x16x32_bf16(pa[2 * hf + 1].v, vf1, acc[db], 0, 0, 0);
            }
        }
    }

    float lq[4];
#pragma unroll
    for (int rg = 0; rg < 4; ++rg) lq[rg] = __shfl(l, quad * 4 + rg);
#pragma unroll
    for (int db = 0; db < 4; ++db) {
#pragma unroll
        for (int rg = 0; rg < 4; ++rg) {
            int row = qbase + w * 16 + quad * 4 + rg;
            y[((size_t)(b * Tn + row) * Hn + h) * HDn + db * 16 + l16] =
                f2bf(acc[db][rg] / lq[rg]);
        }
    }
}

// ---------------- launch ---------------------------------------------------------
extern "C" void kernel_launch(void* const* d_in, const int* in_sizes, int n_in,
                              void* d_out, int out_size, void* d_ws, size_t ws_size,
                              hipStream_t stream) {
    const float* x    = (const float*)d_in[0];
    const float* cosp = (const float*)d_in[1];
    const float* sinp = (const float*)d_in[2];
    const float* wq   = (const float*)d_in[3];
    const float* wk   = (const float*)d_in[4];
    const float* wv   = (const float*)d_in[5];
    const float* wo   = (const float*)d_in[6];
    const float* wfc  = (const float*)d_in[7];
    const float* wpr  = (const float*)d_in[8];
    const float* g1   = (const float*)d_in[9];
    const float* g2   = (const float*)d_in[10];
    float* out = (float*)d_out;

    const size_t S = (size_t)Bn * Tn * Cn;  // 3,145,728 elems
    const size_t MN = S;
    char* W = (char*)d_ws;
    u16* slotA = (u16*)W;                   // [0,2S): h, then h2
    u16* qkvb  = (u16*)(W + 2 * S);         // [2S,8S): qkv bf16
    u16* yh    = (u16*)(W + 2 * S);         // [2S,4S): y bf16 (after prep)
    float* wop = (float*)(W + 4 * S);       // 2 slabs of MN fp32
    u16* fbuf  = (u16*)(W + 4 * S);         // [4S,12S): FF bf16
    u16* qhb   = (u16*)(W + 8 * S);
    u16* khb   = (u16*)(W + 10 * S);
    u16* vtpb  = (u16*)(W + 12 * S);
    float* x1  = (float*)(W + 14 * S);
    u16* wt_qkv = (u16*)(W + 18 * S);
    u16* wt_o   = wt_qkv + (size_t)QKVS * Cn;
    u16* wt_fc  = wt_o + (size_t)Cn * Cn;
    u16* wt_pr  = wt_fc + (size_t)FFn * Cn;
    const size_t WB = ((size_t)QKVS * Cn + (size_t)Cn * Cn + 2 * (size_t)FFn * Cn) * 2;
    float* q0    = (float*)W;                  // wpr slab 0 (reuses [0,4S))
    float* qrest = (float*)(W + 18 * S + WB);  // wpr slabs 1,2

    const int M = Bn * Tn;  // 4096

    // transposes + rmsnorm1 in one launch
    prologue_kernel<<<6912 + M, 256, 0, stream>>>(wq, wk, wv, wo, wfc, wpr,
                                                  wt_qkv, wt_o, wt_fc, wt_pr,
                                                  x, g1, slotA);

    // qkv = h @ [wq|wk|wv] -> bf16
    gemm_bt<3, 4><<<dim3(QKVS / 128, M / 128), 256, 0, stream>>>(slotA, wt_qkv, nullptr,
                                                                 qkvb, M, QKVS, Cn);

    rope_prep_kernel<<<dim3(Tn / 64, Bn * Hn), 256, 0, stream>>>(qkvb, cosp, sinp,
                                                                 qhb, khb, vtpb);

    attn_v4b_kernel<<<Bn * Hn * (Tn / 64), 256, 0, stream>>>(qhb, khb, vtpb, yh);

    // y @ wo, split-K=2 -> fp32 partials (slabs contiguous: P0=wop, P1=wop+MN)
    gemm_bt_part<2><<<dim3(Cn / 64, M / 128, 2), 256, 0, stream>>>(yh, wt_o, wop, wop + MN,
                                                                   M, Cn, Cn, Cn / 2);
    // x1 = x + p0 + p1 ; h2 = rmsnorm(x1, g2)
    reduce2_rmsnorm_kernel<<<M, 256, 0, stream>>>(wop, wop + MN, x, g2, x1, slotA);

    // f = relu(h2 @ wfc)^2 -> bf16
    gemm_bt<2, 4><<<dim3(FFn / 128, M / 128), 256, 0, stream>>>(slotA, wt_fc, nullptr,
                                                                fbuf, M, FFn, Cn);

    // f @ wpr, split-K=3 (Kc=1024), 128x128 tiles (NI=4): z=0 -> q0, z=1,2 -> qrest
    gemm_bt_part<4><<<dim3(Cn / 128, M / 128, 3), 256, 0, stream>>>(fbuf, wt_pr, q0, qrest,
                                                                    M, Cn, FFn, FFn / 3);

    // out = x1 + q0 + qrest0 + qrest1
    reduce_final_kernel<<<(int)(MN / 1024), 256, 0, stream>>>(q0, qrest, x1, out);
}